// Round 9
// baseline (139.938 us; speedup 1.0000x reference)
//
#include <hip/hip_runtime.h>

// RFCM loss, fused single pass + finalize. B=2, K=4, D=H=W=128. Scalar out.
//
// mean(J1) = (1/(B*N)) * sum_{b,k} [ A_bk - Sim_bk^2 / Sm_bk ]
//   Sm=sum mem, Sim=sum mem*img, A=sum mem*img^2, mem=y_pred^2
// mean(J2) = (1/(B*N)) * sum_n [ Sm*Sbk - Sm^2 - sum_k m*bk + sum_k m^2 ]
//   bk = box27(mem_k) incl center, zero pad.
//
// R9: discriminating experiment for the ~1 KB/250cyc/CU GLD-path invariant
// (R7 432 KB/CU in 46us, R8 480 KB/CU in 48us). Ring-4 LDS + raw
// "s_waitcnt vmcnt(5) lgkmcnt(0); s_barrier": plane d+3 issued in region i,
// only batches >=2 regions old are drained at the barrier (the newest 5 GLDs
// stay outstanding across it -- impossible with __syncthreads' vmcnt(0)).
// iv prefetched 1 region ahead, issued BEFORE the GLD batch so in-order
// vmcnt leaves only the GLD batch outstanding. Slot ring: region i writes
// slot i&3, reads slot (i+2)&3 -> intra-region reorder is harmless.
// NEVER __launch_bounds__ min-waves (R4/R6: VGPR=64 -> 240-330MB spills).

#define BB 2
#define KK 4
#define DD 128
#define HH 128
#define WW 128
#define PLANE (HH * WW)
#define SD 8
#define NBD (DD / SD)   // 16
#define HR 8            // rows owned per block
#define NBH (HH / HR)   // 16
#define NT 256          // 32 w-lanes x 8 rows; wave = cluster
#define LROW 128
#define LPL (10 * LROW)        // 10 rows per (plane,cluster)
#define LBUF (KK * LPL)        // 5120 floats = 20 KB per plane buffer

typedef const void __attribute__((address_space(1))) gvoid_t;
typedef void __attribute__((address_space(3))) svoid_t;
#define GLD(gp, lp) __builtin_amdgcn_global_load_lds((gvoid_t*)(gp), (svoid_t*)(lp), 16, 0, 0)

// barrier that drains everything EXCEPT the newest GLD batch (5 per wave)
#define PIPE_BARRIER() asm volatile("s_waitcnt vmcnt(5) lgkmcnt(0)\n\ts_barrier" ::: "memory")
#define ISSUE_FENCE()  asm volatile("" ::: "memory")

__global__ __launch_bounds__(NT) void rfcm_main(
    const float* __restrict__ yp, const float* __restrict__ img,
    double* __restrict__ ws)
{
    __shared__ __align__(16) float sbuf[4 * LBUF];   // 80 KB ring of 4 planes

    const int tid = threadIdx.x;
    const int wl  = tid & 31;       // w-lane: owns cols c0..c0+3
    const int hr  = tid >> 5;       // 0..7: own row
    const int c0  = wl << 2;

    // XCD swizzle: 32 slabs (b,dsb) x 16 h-tiles; slab -> XCD slab%8.
    const int bid  = blockIdx.x;
    const int xcd  = bid & 7;
    const int idx  = bid >> 3;       // 0..63
    const int sl   = idx >> 4;       // 0..3
    const int ht   = idx & 15;
    const int slab = sl * 8 + xcd;   // 0..31
    const int b    = slab >> 4;
    const int dsb  = slab & 15;

    const int h0 = ht * HR;
    const int d0 = dsb * SD;
    const int h  = h0 + hr;

    // ---- DMA staging: wave wv stages cluster wv; 5 two-row 64-lane GLDs ----
    const int wv = tid >> 6;            // 0..3 == cluster
    const int L  = tid & 63;
    const int rr = L >> 5;              // row within 2-row chunk
    const int cl = (L & 31) << 2;       // col (floats)

    auto dma_plane = [&](int t, int slot) {
        if ((unsigned)t >= (unsigned)DD) return;
        const float* pb = yp + (size_t)((b * KK + wv) * DD + t) * PLANE;
        #pragma unroll
        for (int c = 0; c < 5; c++) {
            const int r = (c << 1) + rr;          // lds row 0..9
            int g = h0 - 1 + r;                   // global row, clamped
            g = g < 0 ? 0 : (g > HH - 1 ? HH - 1 : g);
            const float* gp = pb + g * WW + cl;
            float* lp = &sbuf[slot * LBUF + wv * LPL + (c << 1) * LROW];
            GLD(gp, lp);
        }
    };

    const bool okL = (wl > 0), okR = (wl < 31);
    const float msc = (h > 0)      ? 1.f : 0.f;
    const float psc = (h < HH - 1) ? 1.f : 0.f;

    auto extract = [&](int slot, int k, float4& s9, float4& mm) {
        const float* p3 = &sbuf[slot * LBUF + k * LPL + hr * LROW + c0];
        const float4 a4 = *(const float4*)(p3);              // row h-1
        const float4 b4 = *(const float4*)(p3 + LROW);       // row h
        const float4 c4 = *(const float4*)(p3 + 2 * LROW);   // row h+1
        const float4 sb = make_float4(b4.x*b4.x, b4.y*b4.y, b4.z*b4.z, b4.w*b4.w);
        mm = sb;
        float4 v;
        v.x = fmaf(a4.x*a4.x, msc, fmaf(c4.x*c4.x, psc, sb.x));
        v.y = fmaf(a4.y*a4.y, msc, fmaf(c4.y*c4.y, psc, sb.y));
        v.z = fmaf(a4.z*a4.z, msc, fmaf(c4.z*c4.z, psc, sb.z));
        v.w = fmaf(a4.w*a4.w, msc, fmaf(c4.w*c4.w, psc, sb.w));
        const float vL = okL ? __shfl_up(v.w, 1)   : 0.f;
        const float vR = okR ? __shfl_down(v.x, 1) : 0.f;
        s9.x = vL  + v.x + v.y;
        s9.y = v.x + v.y + v.z;
        s9.z = v.y + v.z + v.w;
        s9.w = v.z + v.w + vR;
    };

    const float* imgb = img + (size_t)b * DD * PLANE + h * WW + c0;

    // ---- prolog: planes d0-1,d0 (slots 0,1) needed now; d0+1,d0+2 (2,3)
    // for regions 0,1. iv(d0) issued between -> vmcnt(10) leaves the two
    // newest batches outstanding, forces slots 0,1 + iv landed.
    dma_plane(d0 - 1, 0);
    dma_plane(d0,     1);
    float4 iv = *(const float4*)(imgb + (size_t)d0 * PLANE);
    ISSUE_FENCE();
    dma_plane(d0 + 1, 2);
    dma_plane(d0 + 2, 3);
    asm volatile("s_waitcnt vmcnt(10) lgkmcnt(0)\n\ts_barrier" ::: "memory");

    float4 s9p[KK], s9c[KK], mc[KK], dum;
    const bool vprev = (d0 > 0);
    #pragma unroll
    for (int k = 0; k < KK; k++) {
        if (vprev) extract(0, k, s9p[k], dum);
        else       s9p[k] = make_float4(0.f, 0.f, 0.f, 0.f);
        extract(1, k, s9c[k], mc[k]);
    }

    float smf[KK] = {0,0,0,0}, sif[KK] = {0,0,0,0}, saf[KK] = {0,0,0,0};
    float j2f = 0.f;

    // region i: barrier (drain >=2-region-old); issue iv(d+1); issue GLD(d+3)
    // into slot i&3; consume plane d+1 from slot (i+2)&3.
    #pragma unroll
    for (int i = 0; i < SD; i++) {
        const int d = d0 + i;
        PIPE_BARRIER();                  // forces GLD(d+1) + iv(d) landed

        float4 ivn = iv;
        if (i < SD - 1) ivn = *(const float4*)(imgb + (size_t)(d + 1) * PLANE);
        ISSUE_FENCE();                   // keep iv older than the GLD batch
        if (i < SD - 2) dma_plane(d + 3, i & 3);

        const bool vn = (d + 1 < DD);
        const float4 iv2 = make_float4(iv.x*iv.x, iv.y*iv.y, iv.z*iv.z, iv.w*iv.w);

        float4 summ  = make_float4(0.f, 0.f, 0.f, 0.f);
        float4 sumbk = make_float4(0.f, 0.f, 0.f, 0.f);
        float4 cross = make_float4(0.f, 0.f, 0.f, 0.f);

        #pragma unroll
        for (int k = 0; k < KK; k++) {
            float4 s9n, mn;
            if (vn) extract((i + 2) & 3, k, s9n, mn);
            else { s9n = make_float4(0.f,0.f,0.f,0.f); mn = s9n; }

            const float4 m = mc[k];
            float4 bk;
            bk.x = s9p[k].x + s9c[k].x + s9n.x;
            bk.y = s9p[k].y + s9c[k].y + s9n.y;
            bk.z = s9p[k].z + s9c[k].z + s9n.z;
            bk.w = s9p[k].w + s9c[k].w + s9n.w;

            summ.x += m.x; summ.y += m.y; summ.z += m.z; summ.w += m.w;
            sumbk.x += bk.x; sumbk.y += bk.y; sumbk.z += bk.z; sumbk.w += bk.w;
            cross.x = fmaf(m.x, bk.x - m.x, cross.x);
            cross.y = fmaf(m.y, bk.y - m.y, cross.y);
            cross.z = fmaf(m.z, bk.z - m.z, cross.z);
            cross.w = fmaf(m.w, bk.w - m.w, cross.w);

            smf[k] += (m.x + m.y) + (m.z + m.w);
            sif[k] = fmaf(m.x, iv.x,  fmaf(m.y, iv.y,  fmaf(m.z, iv.z,  fmaf(m.w, iv.w,  sif[k]))));
            saf[k] = fmaf(m.x, iv2.x, fmaf(m.y, iv2.y, fmaf(m.z, iv2.z, fmaf(m.w, iv2.w, saf[k]))));

            s9p[k] = s9c[k]; s9c[k] = s9n; mc[k] = mn;
        }

        j2f += (summ.x * (sumbk.x - summ.x) - cross.x)
             + (summ.y * (sumbk.y - summ.y) - cross.y)
             + (summ.z * (sumbk.z - summ.z) - cross.z)
             + (summ.w * (sumbk.w - summ.w) - cross.w);

        iv = ivn;
    }

    // ---- block reduction of 13 scalars ----
    double q[13];
    #pragma unroll
    for (int k = 0; k < KK; k++) {
        q[k] = (double)smf[k]; q[4 + k] = (double)sif[k]; q[8 + k] = (double)saf[k];
    }
    q[12] = (double)j2f;

    #pragma unroll
    for (int qq = 0; qq < 13; qq++) {
        double v = q[qq];
        #pragma unroll
        for (int off = 32; off > 0; off >>= 1) v += __shfl_down(v, off, 64);
        q[qq] = v;
    }

    __syncthreads();                 // full drain once; sbuf reuse as scratch
    double* red = (double*)sbuf;
    const int lane = tid & 63, wid = tid >> 6;
    if (lane == 0) {
        #pragma unroll
        for (int qq = 0; qq < 13; qq++) red[wid * 13 + qq] = q[qq];
    }
    __syncthreads();
    if (tid < 13) {
        const double sfin = red[tid] + red[13 + tid] + red[26 + tid] + red[39 + tid];
        int idxo;
        if      (tid < 4)  idxo = b * KK + tid;              // Sm
        else if (tid < 8)  idxo = 8  + b * KK + (tid - 4);   // Sim
        else if (tid < 12) idxo = 16 + b * KK + (tid - 8);   // A
        else               idxo = 24;                        // J2
        unsafeAtomicAdd(&ws[idxo], sfin);
    }
}

__global__ void rfcm_fin(const double* __restrict__ ws, float* __restrict__ out)
{
    if (threadIdx.x == 0 && blockIdx.x == 0) {
        double j1 = 0;
        #pragma unroll
        for (int i = 0; i < BB * KK; i++)
            j1 += ws[16 + i] - ws[8 + i] * ws[8 + i] / ws[i];
        const double invBN = 1.0 / ((double)BB * (double)DD * (double)HH * (double)WW);
        out[0] = (float)(j1 * invBN + 0.0008 * ws[24] * invBN);
    }
}

extern "C" void kernel_launch(void* const* d_in, const int* in_sizes, int n_in,
                              void* d_out, int out_size, void* d_ws, size_t ws_size,
                              hipStream_t stream) {
    const float* yp  = (const float*)d_in[0];   // y_pred [2,4,128,128,128]
    const float* img = (const float*)d_in[1];   // image  [2,1,128,128,128]
    float* out = (float*)d_out;
    double* ws = (double*)d_ws;

    hipMemsetAsync(d_ws, 0, 25 * sizeof(double), stream);

    dim3 grid(BB * NBD * NBH);   // 512 blocks, 2 blocks/CU (80 KB LDS each)
    rfcm_main<<<grid, NT, 0, stream>>>(yp, img, ws);
    rfcm_fin<<<1, 64, 0, stream>>>(ws, out);
}

// Round 10
// 122.367 us; speedup vs baseline: 1.1436x; 1.1436x over previous
//
#include <hip/hip_runtime.h>

// RFCM loss, fused single pass + finalize. B=2, K=4, D=H=W=128. Scalar out.
//
// mean(J1) = (1/(B*N)) * sum_{b,k} [ A_bk - Sim_bk^2 / Sm_bk ]
//   Sm=sum mem, Sim=sum mem*img, A=sum mem*img^2, mem=y_pred^2
// mean(J2) = (1/(B*N)) * sum_n [ Sm*Sbk - Sm^2 - sum_k m*bk + sum_k m^2 ]
//   bk = box27(mem_k) incl center, zero pad.
//
// R10: barrier-free waves. Invariant so far: 5 structurally different
// kernels all fetch at 0.9-1.2 TB/s; common factor = cross-wave coupling
// (s_barrier convoy / compiler-serialized register consumption). Here each
// wave owns a private LDS slice (its 2 rows + halo, 4 clusters), stages it
// with 8 fire-and-forget global_load_lds per plane, double-buffered, and
// syncs ONLY via s_waitcnt vmcnt(0) (builtin, not inline asm -- R9's asm
// blew VGPR to 256). No s_barrier in the whole d-march; waves never wait
// on each other. d-ring (s9p/s9c/mc) in registers.
// NEVER __launch_bounds__ min-waves (R4/R6: VGPR=64 -> 240-330MB spills).

#define BB 2
#define KK 4
#define DD 128
#define HH 128
#define WW 128
#define PLANE (HH * WW)
#define SD 8
#define NBD (DD / SD)   // 16
#define HR 8            // rows per block (4 waves x 2 rows)
#define NBH (HH / HR)   // 16
#define NT 256
#define SLROW 128
#define SLICE (KK * 4 * SLROW)   // 4 rows per cluster = 2048 floats = 8 KB

typedef const void __attribute__((address_space(1))) gvoid_t;
typedef void __attribute__((address_space(3))) svoid_t;
#define GLD(gp, lp) __builtin_amdgcn_global_load_lds((gvoid_t*)(gp), (svoid_t*)(lp), 16, 0, 0)
// wait vmcnt(0), leave lgkm(15)/exp(7) unconstrained: [3:0]vm_lo [6:4]exp [11:8]lgkm [15:14]vm_hi
#define WAIT_VM0() __builtin_amdgcn_s_waitcnt(0x0F70)

__global__ __launch_bounds__(NT) void rfcm_main(
    const float* __restrict__ yp, const float* __restrict__ img,
    double* __restrict__ ws)
{
    __shared__ __align__(16) float sbuf[4 * 2 * SLICE];   // 64 KB: [wave][buf][slice]

    const int tid = threadIdx.x;
    const int wv  = tid >> 6;       // wave 0..3
    const int L   = tid & 63;
    const int wl  = L & 31;         // w-lane: owns cols c0..c0+3
    const int hy  = L >> 5;         // 0..1: own row within wave pair
    const int c0  = wl << 2;

    // XCD swizzle: slab (b,dsb) -> XCD slab%8; its 16 h-tiles share one L2.
    const int bid  = blockIdx.x;
    const int xcd  = bid & 7;
    const int idx  = bid >> 3;       // 0..63
    const int sl   = idx >> 4;       // 0..3
    const int ht   = idx & 15;
    const int slab = sl * 8 + xcd;   // 0..31
    const int b    = slab >> 4;
    const int dsb  = slab & 15;

    const int h0  = ht * HR;
    const int hp0 = h0 + (wv << 1);  // wave's first owned row
    const int h   = hp0 + hy;        // own row
    const int d0  = dsb * SD;

    float* const mybuf = &sbuf[wv * 2 * SLICE];

    // ---- wave-private DMA batch: plane t -> buf (t&1). 8 GLDs of 1 KB. ----
    // slice layout per cluster: 4 rows (hp0-1 .. hp0+2, h-clamped) x 128.
    const int rr = L >> 5;              // row within 2-row chunk
    const int cl = (L & 31) << 2;       // col (floats)

    auto dma_batch = [&](int t) {
        if ((unsigned)t >= (unsigned)DD) return;
        float* const bb = mybuf + (t & 1) * SLICE;
        #pragma unroll
        for (int k = 0; k < KK; k++) {
            const float* pb = yp + (size_t)((b * KK + k) * DD + t) * PLANE;
            #pragma unroll
            for (int rp = 0; rp < 2; rp++) {
                int g = hp0 - 1 + (rp << 1) + rr;     // global row, clamp
                g = g < 0 ? 0 : (g > HH - 1 ? HH - 1 : g);
                const float* gp = pb + g * WW + cl;
                float* lp = bb + (k * 4 + (rp << 1)) * SLROW;
                GLD(gp, lp);
            }
        }
    };

    const bool okL = (wl > 0), okR = (wl < 31);
    const float msc = (h > 0)      ? 1.f : 0.f;
    const float psc = (h < HH - 1) ? 1.f : 0.f;

    // extract hw9 + center squares for cluster k from plane t's buffer
    auto extract = [&](int t, int k, float4& s9, float4& mm) {
        const float* p3 = mybuf + (t & 1) * SLICE + (k * 4 + hy) * SLROW + c0;
        const float4 a4 = *(const float4*)(p3);               // row h-1
        const float4 b4 = *(const float4*)(p3 + SLROW);       // row h
        const float4 c4 = *(const float4*)(p3 + 2 * SLROW);   // row h+1
        const float4 sb = make_float4(b4.x*b4.x, b4.y*b4.y, b4.z*b4.z, b4.w*b4.w);
        mm = sb;
        float4 v;
        v.x = fmaf(a4.x*a4.x, msc, fmaf(c4.x*c4.x, psc, sb.x));
        v.y = fmaf(a4.y*a4.y, msc, fmaf(c4.y*c4.y, psc, sb.y));
        v.z = fmaf(a4.z*a4.z, msc, fmaf(c4.z*c4.z, psc, sb.z));
        v.w = fmaf(a4.w*a4.w, msc, fmaf(c4.w*c4.w, psc, sb.w));
        const float vL = okL ? __shfl_up(v.w, 1)   : 0.f;
        const float vR = okR ? __shfl_down(v.x, 1) : 0.f;
        s9.x = vL  + v.x + v.y;
        s9.y = v.x + v.y + v.z;
        s9.z = v.y + v.z + v.w;
        s9.w = v.z + v.w + vR;
    };

    const float* imgb = img + (size_t)b * DD * PLANE + h * WW + c0;

    // ---- prolog (no barrier anywhere) ----
    dma_batch(d0 - 1);                       // no-op when d0==0
    dma_batch(d0);
    float4 iv = *(const float4*)(imgb + (size_t)d0 * PLANE);
    WAIT_VM0();

    float4 s9p[KK], s9c[KK], mc[KK], dum;
    const bool vprev = (d0 > 0);
    #pragma unroll
    for (int k = 0; k < KK; k++) {
        if (vprev) extract(d0 - 1, k, s9p[k], dum);
        else       s9p[k] = make_float4(0.f, 0.f, 0.f, 0.f);
        extract(d0, k, s9c[k], mc[k]);
    }
    dma_batch(d0 + 1);                       // into buf[(d0+1)&1] (over d0-1)

    float smf[KK] = {0,0,0,0}, sif[KK] = {0,0,0,0}, saf[KK] = {0,0,0,0};
    float j2f = 0.f;

    // region i (plane d): wait B(d+1)+iv(d); issue iv(d+1), B(d+2); compute.
    #pragma unroll 2
    for (int i = 0; i < SD; i++) {
        const int d = d0 + i;
        WAIT_VM0();                          // B(d+1) + iv(d) landed

        float4 ivn = iv;
        if (i < SD - 1) ivn = *(const float4*)(imgb + (size_t)(d + 1) * PLANE);
        if (i <= SD - 2) dma_batch(d + 2);   // buf[(d+2)&1] = plane-d buffer,
                                             // consumed last region (wave-private
                                             // program order => no race)
        const bool vn = (d + 1 < DD);
        const float4 iv2 = make_float4(iv.x*iv.x, iv.y*iv.y, iv.z*iv.z, iv.w*iv.w);

        float4 summ  = make_float4(0.f, 0.f, 0.f, 0.f);
        float4 sumbk = make_float4(0.f, 0.f, 0.f, 0.f);
        float4 cross = make_float4(0.f, 0.f, 0.f, 0.f);

        #pragma unroll
        for (int k = 0; k < KK; k++) {
            float4 s9n, mn;
            if (vn) extract(d + 1, k, s9n, mn);
            else { s9n = make_float4(0.f,0.f,0.f,0.f); mn = s9n; }

            const float4 m = mc[k];
            float4 bk;
            bk.x = s9p[k].x + s9c[k].x + s9n.x;
            bk.y = s9p[k].y + s9c[k].y + s9n.y;
            bk.z = s9p[k].z + s9c[k].z + s9n.z;
            bk.w = s9p[k].w + s9c[k].w + s9n.w;

            summ.x += m.x; summ.y += m.y; summ.z += m.z; summ.w += m.w;
            sumbk.x += bk.x; sumbk.y += bk.y; sumbk.z += bk.z; sumbk.w += bk.w;
            cross.x = fmaf(m.x, bk.x - m.x, cross.x);
            cross.y = fmaf(m.y, bk.y - m.y, cross.y);
            cross.z = fmaf(m.z, bk.z - m.z, cross.z);
            cross.w = fmaf(m.w, bk.w - m.w, cross.w);

            smf[k] += (m.x + m.y) + (m.z + m.w);
            sif[k] = fmaf(m.x, iv.x,  fmaf(m.y, iv.y,  fmaf(m.z, iv.z,  fmaf(m.w, iv.w,  sif[k]))));
            saf[k] = fmaf(m.x, iv2.x, fmaf(m.y, iv2.y, fmaf(m.z, iv2.z, fmaf(m.w, iv2.w, saf[k]))));

            s9p[k] = s9c[k]; s9c[k] = s9n; mc[k] = mn;
        }

        j2f += (summ.x * (sumbk.x - summ.x) - cross.x)
             + (summ.y * (sumbk.y - summ.y) - cross.y)
             + (summ.z * (sumbk.z - summ.z) - cross.z)
             + (summ.w * (sumbk.w - summ.w) - cross.w);

        iv = ivn;
    }

    // ---- block reduction of 13 scalars (first barrier in the kernel) ----
    double q[13];
    #pragma unroll
    for (int k = 0; k < KK; k++) {
        q[k] = (double)smf[k]; q[4 + k] = (double)sif[k]; q[8 + k] = (double)saf[k];
    }
    q[12] = (double)j2f;

    #pragma unroll
    for (int qq = 0; qq < 13; qq++) {
        double v = q[qq];
        #pragma unroll
        for (int off = 32; off > 0; off >>= 1) v += __shfl_down(v, off, 64);
        q[qq] = v;
    }

    __syncthreads();
    double* red = (double*)sbuf;
    const int lane = tid & 63, wid = tid >> 6;
    if (lane == 0) {
        #pragma unroll
        for (int qq = 0; qq < 13; qq++) red[wid * 13 + qq] = q[qq];
    }
    __syncthreads();
    if (tid < 13) {
        const double sfin = red[tid] + red[13 + tid] + red[26 + tid] + red[39 + tid];
        int idxo;
        if      (tid < 4)  idxo = b * KK + tid;              // Sm
        else if (tid < 8)  idxo = 8  + b * KK + (tid - 4);   // Sim
        else if (tid < 12) idxo = 16 + b * KK + (tid - 8);   // A
        else               idxo = 24;                        // J2
        unsafeAtomicAdd(&ws[idxo], sfin);
    }
}

__global__ void rfcm_fin(const double* __restrict__ ws, float* __restrict__ out)
{
    if (threadIdx.x == 0 && blockIdx.x == 0) {
        double j1 = 0;
        #pragma unroll
        for (int i = 0; i < BB * KK; i++)
            j1 += ws[16 + i] - ws[8 + i] * ws[8 + i] / ws[i];
        const double invBN = 1.0 / ((double)BB * (double)DD * (double)HH * (double)WW);
        out[0] = (float)(j1 * invBN + 0.0008 * ws[24] * invBN);
    }
}

extern "C" void kernel_launch(void* const* d_in, const int* in_sizes, int n_in,
                              void* d_out, int out_size, void* d_ws, size_t ws_size,
                              hipStream_t stream) {
    const float* yp  = (const float*)d_in[0];   // y_pred [2,4,128,128,128]
    const float* img = (const float*)d_in[1];   // image  [2,1,128,128,128]
    float* out = (float*)d_out;
    double* ws = (double*)d_ws;

    hipMemsetAsync(d_ws, 0, 25 * sizeof(double), stream);

    dim3 grid(BB * NBD * NBH);   // 512 blocks, 2/CU (64 KB LDS each)
    rfcm_main<<<grid, NT, 0, stream>>>(yp, img, ws);
    rfcm_fin<<<1, 64, 0, stream>>>(ws, out);
}